// Round 10
// baseline (1176.466 us; speedup 1.0000x reference)
//
#include <hip/hip_runtime.h>

#define IN_CAPS 2048
#define OD      512                 // out_caps(32) * out_dim(16)
#define ICH_P   8                   // i's per pass block
#define NIC     (IN_CAPS / ICH_P)   // 256 i-chunks (= partial slices)

__device__ __forceinline__ float dot4(const float4& a, const float4& b) {
    return fmaf(a.x, b.x, fmaf(a.y, b.y, fmaf(a.z, b.z, a.w * b.w)));
}

// Recompute pass (u_hat never materialized -- R2-R8 lesson).
// MODE 0: s0 partials = sum_i u (scale 1/32 at reduce).
// MODE 1: a = u.v0; bij = a; c = softmax_o(a); s1 partials += c*u.
// MODE 2: a = u.v1 + bij; c = softmax; s2 partials.
// R9 lesson: MODE0 == MODE1/2 duration -> stall is the load pipeline, not
// softmax. This version: 1 od/thread (512-thr block) so W fits a register
// DOUBLE BUFFER (wc/wn), and x is staged in LDS (broadcast ds_read) killing
// the per-bb scalar-load stall chain (R9: 128 SGPRs/ii forced JIT s_loads).
// Grid 2048 = NIC*8; XCD swizzle: 8 b-chunk blocks of an i-chunk share s&7
// -> same XCD -> W window fetched into one L2.
template<int MODE>
__global__ __launch_bounds__(512, 4)
void k_pass(const float* __restrict__ x,     // [64][2048][16]
            const float* __restrict__ W,     // [2048][512][16]
            const float* __restrict__ v,     // [64][512] (MODE 1,2)
            float* __restrict__ bij,         // [64][2048][32]
            float* __restrict__ part)        // [64][NIC][512]
{
    const int t  = threadIdx.x;                   // od = t
    const int s  = blockIdx.x;                    // 0..2047
    const int ic = (s & 7) + 8 * (s >> 6);        // 0..255
    const int bc = (s >> 3) & 7;                  // b-chunk
    const int i0 = ic * ICH_P;
    const int b0 = bc * 8;

    __shared__ float xs[8][ICH_P][16];            // 4 KB
    __shared__ float a_buf[8][32];
    __shared__ float c_buf[8][32];

    if (t < 256) {   // 256 float4 = 8 bb x 8 ii x 4 quads
        const int bb = t >> 5, ii = (t >> 2) & 7, q = t & 3;
        *(float4*)&xs[bb][ii][4 * q] = *(const float4*)(
            x + ((size_t)(b0 + bb) * IN_CAPS + i0 + ii) * 16 + 4 * q);
    }
    __syncthreads();

    float vr[8];
    if (MODE != 0) {
#pragma unroll
        for (int bb = 0; bb < 8; ++bb)
            vr[bb] = v[(size_t)(b0 + bb) * OD + t];
    }

    float acc[8];
#pragma unroll
    for (int bb = 0; bb < 8; ++bb) acc[bb] = 0.f;

    float4 wc[4], wn[4];
    {
        const float4* wp = (const float4*)(W + ((size_t)i0 * OD + t) * 16);
#pragma unroll
        for (int q = 0; q < 4; ++q) wc[q] = wp[q];
    }

    for (int ii = 0; ii < ICH_P; ++ii) {
        const int i = i0 + ii;
        if (ii + 1 < ICH_P) {
            const float4* wp = (const float4*)(W + ((size_t)(i + 1) * OD + t) * 16);
#pragma unroll
            for (int q = 0; q < 4; ++q) wn[q] = wp[q];   // prefetch next W row
        }

        float u[8];
#pragma unroll
        for (int bb = 0; bb < 8; ++bb) {
            const float4 xa = *(const float4*)&xs[bb][ii][0];
            const float4 xb = *(const float4*)&xs[bb][ii][4];
            const float4 xc = *(const float4*)&xs[bb][ii][8];
            const float4 xd = *(const float4*)&xs[bb][ii][12];
            u[bb] = dot4(wc[0], xa) + dot4(wc[1], xb)
                  + dot4(wc[2], xc) + dot4(wc[3], xd);
        }

        if (MODE == 0) {
#pragma unroll
            for (int bb = 0; bb < 8; ++bb) acc[bb] += u[bb];
        } else {
            // per-o agreement: reduce u*v over the 16-thread od-group
#pragma unroll
            for (int bb = 0; bb < 8; ++bb) {
                float ap = u[bb] * vr[bb];
                ap += __shfl_xor(ap, 1);
                ap += __shfl_xor(ap, 2);
                ap += __shfl_xor(ap, 4);
                ap += __shfl_xor(ap, 8);
                if ((t & 15) == 0) a_buf[bb][t >> 4] = ap;
            }
            __syncthreads();
            if (t < 256) {   // thread (b = t>>5, o = t&31): bij + softmax
                const int b = t >> 5;
                const int o = t & 31;
                float a = a_buf[b][o];
                float* bp = bij + ((size_t)(b0 + b) * IN_CAPS + i) * 32 + o;
                if (MODE == 1) *bp = a;
                else           a += *bp;
                float m = a;
#pragma unroll
                for (int d = 1; d < 32; d <<= 1) m = fmaxf(m, __shfl_xor(m, d));
                const float e = __expf(a - m);
                float sum = e;
#pragma unroll
                for (int d = 1; d < 32; d <<= 1) sum += __shfl_xor(sum, d);
                c_buf[b][o] = e / sum;
            }
            __syncthreads();
#pragma unroll
            for (int bb = 0; bb < 8; ++bb)
                acc[bb] = fmaf(c_buf[bb][t >> 4], u[bb], acc[bb]);
        }

        if (ii + 1 < ICH_P) {
#pragma unroll
            for (int q = 0; q < 4; ++q) wc[q] = wn[q];
        }
    }

#pragma unroll
    for (int bb = 0; bb < 8; ++bb)
        part[((size_t)(b0 + bb) * NIC + ic) * OD + t] = acc[bb];
}

// Reduce partials over NC slices, apply scale, squash, write v (or d_out).
template<int NC>
__global__ __launch_bounds__(256)
void k_reduce(const float* __restrict__ part, float* __restrict__ vout,
              float scale, int nb)
{
    const int idx = blockIdx.x * 256 + threadIdx.x;
    if (idx >= nb * OD) return;
    const int b  = idx >> 9;
    const int od = idx & (OD - 1);
    const float* p = part + (size_t)b * NC * OD + od;
    float s = 0.f;
#pragma unroll 8
    for (int ch = 0; ch < NC; ++ch) s += p[(size_t)ch * OD];
    s *= scale;
    const float sq = s * s;
    vout[idx] = sq * s / ((1.f + sq) * sqrtf(sq + 1e-8f));
}

extern "C" void kernel_launch(void* const* d_in, const int* in_sizes, int n_in,
                              void* d_out, int out_size, void* d_ws, size_t ws_size,
                              hipStream_t stream)
{
    const float* x = (const float*)d_in[0];   // [64][2048][16]
    const float* W = (const float*)d_in[1];   // [2048][32][16][16]
    float* out = (float*)d_out;               // [64][32][16][1]

    // workspace: bij 16 MB | part 33.5 MB | v0 128 KB | v1 128 KB
    char* wsc = (char*)d_ws;
    float* bij  = (float*)wsc;
    float* part = (float*)(wsc + (size_t)64 * IN_CAPS * 32 * 4);
    float* v0   = (float*)(wsc + (size_t)64 * IN_CAPS * 32 * 4
                               + (size_t)64 * NIC * OD * 4);
    float* v1   = v0 + (size_t)64 * OD;

    const int rblocks = 64 * OD / 256;   // 128

    k_pass<0><<<2048, 512, 0, stream>>>(x, W, v0 /*unused*/, bij, part);
    k_reduce<NIC><<<rblocks, 256, 0, stream>>>(part, v0, 1.f / 32.f, 64);
    k_pass<1><<<2048, 512, 0, stream>>>(x, W, v0, bij, part);
    k_reduce<NIC><<<rblocks, 256, 0, stream>>>(part, v1, 1.f, 64);
    k_pass<2><<<2048, 512, 0, stream>>>(x, W, v1, bij, part);
    k_reduce<NIC><<<rblocks, 256, 0, stream>>>(part, out, 1.f, 64);
}